// Round 9
// baseline (147.257 us; speedup 1.0000x reference)
//
#include <hip/hip_runtime.h>

#define B_ 4
#define N_ 4096
#define C_ 256
#define M_ 2048

typedef __attribute__((ext_vector_type(8))) short short8;
typedef __attribute__((ext_vector_type(4))) short s16x4;
typedef __attribute__((ext_vector_type(4))) float f32x4;
typedef __attribute__((ext_vector_type(16))) float f32x16;

union U16x8 { uint4 u4; unsigned short us[8]; short8 s8; s16x4 s4[2]; };

__device__ __forceinline__ float bf2f(unsigned short h) {
    unsigned int u = ((unsigned int)h) << 16;
    return __builtin_bit_cast(float, u);
}
__device__ __forceinline__ unsigned short f2bf(float f) {
    unsigned int u = __builtin_bit_cast(unsigned int, f);
    u += 0x7FFFu + ((u >> 16) & 1u);
    return (unsigned short)(u >> 16);
}
// 16B LDS read from an 8B-aligned address (two b64s; avoids b128 align req)
__device__ __forceinline__ short8 lds8(const unsigned short* p) {
    s16x4 lo = *(const s16x4*)p;
    s16x4 hi = *(const s16x4*)(p + 4);
    return __builtin_shufflevector(lo, hi, 0, 1, 2, 3, 4, 5, 6, 7);
}

#define GLB_AS(p) ((const __attribute__((address_space(1))) unsigned int*)(p))
#define LDS_AS(p) ((__attribute__((address_space(3))) unsigned int*)(p))

// ---- Prepass A: invgn[b][m] = 1/max(||g[b][:,m]||, 1e-8). grid (M/64, B) ----
__global__ __launch_bounds__(256) void k_norm(const float* __restrict__ g,
                                              float* __restrict__ invgn) {
    __shared__ float red[4][64];
    const int b = blockIdx.y, m0 = blockIdx.x * 64;
    const int tid = threadIdx.x;
    const int ml = tid & 63, cq = tid >> 6;
    const float* gb = g + (size_t)b * C_ * M_ + m0 + ml;
    float ss = 0.f;
#pragma unroll 8
    for (int i = 0; i < 64; ++i) {
        float v = gb[(size_t)(cq * 64 + i) * M_];
        ss += v * v;
    }
    red[cq][ml] = ss;
    __syncthreads();
    if (cq == 0) {
        float t = red[0][ml] + red[1][ml] + red[2][ml] + red[3][ml];
        invgn[b * M_ + m0 + ml] = 1.f / fmaxf(sqrtf(t), 1e-8f);
    }
}

// ---- Prepass B: gcm = bf16(g)[c][m]; gmc = bf16(g*invgn)[m][c]. grid (M/64, C/64, B) ----
__global__ __launch_bounds__(256) void k_cast(const float* __restrict__ g,
                                              const float* __restrict__ invgn,
                                              unsigned short* __restrict__ gcm,
                                              unsigned short* __restrict__ gmc) {
    __shared__ unsigned short T[64 * 66];
    __shared__ float sInv[64];
    const int b = blockIdx.z, c0 = blockIdx.y * 64, m0 = blockIdx.x * 64;
    const int tid = threadIdx.x;
    if (tid < 64) sInv[tid] = invgn[b * M_ + m0 + tid];
    __syncthreads();
    const float* gbase = g + ((size_t)b * C_ + c0) * M_ + m0;
    unsigned short* gcmb = gcm + ((size_t)b * C_ + c0) * M_ + m0;
#pragma unroll
    for (int j = 0; j < 4; ++j) {
        int id = tid + 256 * j;
        int ci = id >> 4, mq = (id & 15) * 4;
        float4 v = *(const float4*)(gbase + (size_t)ci * M_ + mq);
        uint2 pk;
        pk.x = (unsigned)f2bf(v.x) | ((unsigned)f2bf(v.y) << 16);
        pk.y = (unsigned)f2bf(v.z) | ((unsigned)f2bf(v.w) << 16);
        *(uint2*)(gcmb + (size_t)ci * M_ + mq) = pk;
        T[ci * 66 + mq + 0] = f2bf(v.x * sInv[mq + 0]);
        T[ci * 66 + mq + 1] = f2bf(v.y * sInv[mq + 1]);
        T[ci * 66 + mq + 2] = f2bf(v.z * sInv[mq + 2]);
        T[ci * 66 + mq + 3] = f2bf(v.w * sInv[mq + 3]);
    }
    __syncthreads();
    unsigned short* gmcb = gmc + ((size_t)b * M_ + m0) * C_ + c0;
#pragma unroll
    for (int j = 0; j < 2; ++j) {
        int id = tid + 256 * j;
        int mr = id >> 3, cc8 = (id & 7) * 8;
        U16x8 t;
#pragma unroll
        for (int k = 0; k < 8; ++k) t.us[k] = T[(cc8 + k) * 66 + mr];
        *(uint4*)(gmcb + (size_t)mr * C_ + cc8) = t.u4;
    }
}

// ---------------- Main fused kernel (v8 = v7 with DMA-staged sGcm) ----------------
// 32 rows/block, grid 512, 2 blocks/CU. GEMM1: 4-way key-split, wave = 32 rows x 16 keys
// (Q x2 in regs, ghat read ONCE). GEMM2: mfma 32x32x16, wave = 32 rows x 64-c slice.
// BOTH tiles via async global_load_lds + XOR chunk swizzle (full 2048-chunk coverage each);
// sP padded stride 68. DMA issue staggered between the two barriers.
__global__ __launch_bounds__(256, 2) void k_main(
    const float* __restrict__ l,
    const unsigned short* __restrict__ gcm,    // [B][C][M] raw bf16
    const unsigned short* __restrict__ gmc,    // [B][M][C] normalized bf16
    float* __restrict__ out)
{
    __shared__ __align__(16) unsigned short sGmc[64 * 256];   // ghat [m][c], DMA, 32 KB
    __shared__ __align__(16) unsigned short sGcm[256 * 64];   // raw g [c][m], DMA, 32 KB
    __shared__ __align__(16) unsigned short sP[32 * 68];      // P [n][m], 4352 B
    __shared__ float sDen[4][32];

    const int tid = threadIdx.x;
    const int w = tid >> 6;
    const int lane = tid & 63;
    const int l15 = lane & 15;
    const int quad = lane >> 4;
    const int l31 = lane & 31;
    const int h = lane >> 5;
    const int b = blockIdx.y;
    const int row0 = blockIdx.x * 32;

    // DMA source offsets (shorts): phys chunk p -> swizzled source chunk within row
    int goffA[8], goffB[8];
#pragma unroll
    for (int i = 0; i < 8; ++i) {
        int p = (w * 8 + i) * 64 + lane;                 // physical 16B-chunk index
        int rA = p >> 5;                                 // sGmc: 32 chunks/row (512 B)
        goffA[i] = rA * 256 + (((p & 31) ^ (rA & 31)) << 3);
        int rB = p >> 3;                                 // sGcm: 8 chunks/row (128 B)
        goffB[i] = rB * 2048 + (((p & 7) ^ (rB & 7)) << 3);
    }

    const unsigned short* gmc_b = gmc + (size_t)b * M_ * C_;
    const unsigned short* gcm_b = gcm + (size_t)b * C_ * M_;

    auto dmaA = [&](int m0) {
#pragma unroll
        for (int i = 0; i < 8; ++i)
            __builtin_amdgcn_global_load_lds(GLB_AS(gmc_b + (size_t)m0 * 256 + goffA[i]),
                                             LDS_AS(&sGmc[(w * 8 + i) * 512]), 16, 0, 0);
    };
    auto dmaB = [&](int m0) {
#pragma unroll
        for (int i = 0; i < 8; ++i)
            __builtin_amdgcn_global_load_lds(GLB_AS(gcm_b + (size_t)m0 + goffB[i]),
                                             LDS_AS(&sGcm[(w * 8 + i) * 512]), 16, 0, 0);
    };

    dmaA(0);
    dmaB(0);

    // ---- Q: 2 row-tiles (all 32 block rows), norm, -> bf16 A-frags in regs ----
    short8 qf[2][8];
#pragma unroll
    for (int rt = 0; rt < 2; ++rt) {
        const float* lrow = l + ((size_t)b * N_ + row0 + rt * 16 + l15) * C_;
        U16x8 qt[8];
        float ss = 0.f;
#pragma unroll
        for (int kk = 0; kk < 8; ++kk) {
            float4 x0 = *(const float4*)(lrow + kk * 32 + quad * 8);
            float4 x1 = *(const float4*)(lrow + kk * 32 + quad * 8 + 4);
            ss += x0.x*x0.x + x0.y*x0.y + x0.z*x0.z + x0.w*x0.w;
            ss += x1.x*x1.x + x1.y*x1.y + x1.z*x1.z + x1.w*x1.w;
            qt[kk].us[0] = f2bf(x0.x); qt[kk].us[1] = f2bf(x0.y);
            qt[kk].us[2] = f2bf(x0.z); qt[kk].us[3] = f2bf(x0.w);
            qt[kk].us[4] = f2bf(x1.x); qt[kk].us[5] = f2bf(x1.y);
            qt[kk].us[6] = f2bf(x1.z); qt[kk].us[7] = f2bf(x1.w);
        }
        ss += __shfl_xor(ss, 16);
        ss += __shfl_xor(ss, 32);
        const float invl = 1.0f / fmaxf(sqrtf(ss), 1e-8f);
#pragma unroll
        for (int kk = 0; kk < 8; ++kk) {
            U16x8 t;
#pragma unroll
            for (int j = 0; j < 8; ++j) t.us[j] = f2bf(bf2f(qt[kk].us[j]) * invl);
            qf[rt][kk] = t.s8;
        }
    }

    __syncthreads();   // drains DMA: both tiles of mt=0 resident

    f32x4 zero = {0.f, 0.f, 0.f, 0.f};
    f32x16 o[2];
#pragma unroll
    for (int i = 0; i < 16; ++i) { o[0][i] = 0.f; o[1][i] = 0.f; }
    float dl[2][4] = {{0.f,0.f,0.f,0.f},{0.f,0.f,0.f,0.f}};

    for (int mt = 0; mt < 32; ++mt) {
        // GEMM1: S[32 rows][16 keys] (wave key-slice w), K=256; B read once, used 2x
        f32x4 sa[2];
        sa[0] = zero; sa[1] = zero;
        const int g1row = w * 16 + l15;
#pragma unroll
        for (int kk = 0; kk < 8; ++kk) {
            const int j = ((kk * 4 + quad) ^ (g1row & 31)) << 3;
            short8 bb = *(const short8*)&sGmc[g1row * 256 + j];
            sa[0] = __builtin_amdgcn_mfma_f32_16x16x32_bf16(qf[0][kk], bb, sa[0], 0, 0, 0);
            sa[1] = __builtin_amdgcn_mfma_f32_16x16x32_bf16(qf[1][kk], bb, sa[1], 0, 0, 0);
        }
        // p = exp(cos/tau); denominator partials; write P (stride-68, conflict-free)
#pragma unroll
        for (int rt = 0; rt < 2; ++rt)
#pragma unroll
            for (int r = 0; r < 4; ++r) {
                float p = exp2f(sa[rt][r] * 3.6067376022224085f);  // (1/0.4)*log2(e)
                dl[rt][r] += p;
                sP[(rt * 16 + quad * 4 + r) * 68 + w * 16 + l15] = f2bf(p);
            }
        __syncthreads();                    // barrier A: P complete, sGmc readers done, dmaB drained

        if (mt < 31) dmaA((mt + 1) * 64);   // covered by GEMM2, drained at barrier B

        // GEMM2 (32x32x16): O[32 rows][64-c slice] += P[32][64] * V[64][c-slice]
#pragma unroll
        for (int kk = 0; kk < 4; ++kk) {
            short8 a = lds8(&sP[l31 * 68 + kk * 16 + h * 8]);
#pragma unroll
            for (int ct = 0; ct < 2; ++ct) {
                const int c = w * 64 + ct * 32 + l31;
                const int j = ((kk * 2 + h) ^ (c & 7)) << 3;   // XOR chunk swizzle
                short8 bb = *(const short8*)&sGcm[c * 64 + j];
                o[ct] = __builtin_amdgcn_mfma_f32_32x32x16_bf16(a, bb, o[ct], 0, 0, 0);
            }
        }
        __syncthreads();                    // barrier B: sP/sGcm readers done, dmaA drained
        if (mt < 31) dmaB((mt + 1) * 64);   // covered by next GEMM1, drained at barrier A
    }

    // ---- denominators: reduce over 16 key-lanes, publish per (key-slice, row) ----
#pragma unroll
    for (int rt = 0; rt < 2; ++rt)
#pragma unroll
        for (int r = 0; r < 4; ++r) {
            float d = dl[rt][r];
            d += __shfl_xor(d, 1);
            d += __shfl_xor(d, 2);
            d += __shfl_xor(d, 4);
            d += __shfl_xor(d, 8);
            if (l15 == 0) sDen[w][rt * 16 + quad * 4 + r] = d;
        }
    __syncthreads();

    // ---- epilogue: out = l + O/denom. 32x32 C/D: col=l31, row=(reg&3)+8*(reg>>2)+4*h ----
    const float* lb = l + ((size_t)b * N_ + row0) * C_;
    float* ob = out + ((size_t)b * N_ + row0) * C_;
#pragma unroll
    for (int reg = 0; reg < 16; ++reg) {
        const int row = (reg & 3) + 8 * (reg >> 2) + 4 * h;
        const float inv = 1.f / (sDen[0][row] + sDen[1][row] + sDen[2][row] + sDen[3][row]);
        const size_t rbase = (size_t)row * C_;
#pragma unroll
        for (int ct = 0; ct < 2; ++ct) {
            const int c = w * 64 + ct * 32 + l31;
            ob[rbase + c] = lb[rbase + c] + o[ct][reg] * inv;
        }
    }
}

extern "C" void kernel_launch(void* const* d_in, const int* in_sizes, int n_in,
                              void* d_out, int out_size, void* d_ws, size_t ws_size,
                              hipStream_t stream) {
    (void)in_sizes; (void)n_in; (void)out_size; (void)ws_size;
    const float* l = (const float*)d_in[0];
    const float* g = (const float*)d_in[1];
    float* outp = (float*)d_out;

    char* ws = (char*)d_ws;
    unsigned short* gmc = (unsigned short*)ws;                                   // 4 MB (normalized, [b][m][c])
    unsigned short* gcm = (unsigned short*)(ws + (size_t)B_ * M_ * C_ * 2);      // 4 MB (raw, [b][c][m])
    float* invgn = (float*)(ws + 2 * (size_t)B_ * M_ * C_ * 2);                  // 32 KB

    k_norm<<<dim3(M_ / 64, B_), 256, 0, stream>>>(g, invgn);
    k_cast<<<dim3(M_ / 64, C_ / 64, B_), 256, 0, stream>>>(g, invgn, gcm, gmc);
    k_main<<<dim3(N_ / 32, B_), 256, 0, stream>>>(l, gcm, gmc, outp);
}